// Round 11
// baseline (726.648 us; speedup 1.0000x reference)
//
#include <hip/hip_runtime.h>

#define WW 1280
#define HH 720
#define NB 8
#define NPIX (HH * WW)            // 921600
#define TOTAL (NB * NPIX)         // 7372800

#define FMAX 4.0f
#define RHALO 4
#define TH 16
#define TW 64
#define TPIX (TH * TW)            // 1024
#define TILES_X (WW / TW)         // 20
#define TILES_Y (HH / TH)         // 45
#define TPB (TILES_X * TILES_Y)   // 900
#define NT (NB * TPB)             // 7200
#define WH (TH + 2 * RHALO)       // 24
#define WWIN (TW + 2 * RHALO)     // 72
#define WPOS (WH * WWIN)          // 1728
#define TB 256
#define CAPB 4096

// ---------------------------------------------------------------------------
// K1: per-batch outlier lists.
// ---------------------------------------------------------------------------
__global__ void k1_outliers(const float* __restrict__ flow,
                            const float* __restrict__ depth,
                            int* __restrict__ nOut, int4* __restrict__ lists) {
    int i = blockIdx.x * blockDim.x + threadIdx.x;
    int p4 = i * 4;
    int b = p4 / NPIX;
    int p = p4 - b * NPIX;
    int y = p / WW;
    int x0 = p - y * WW;
    const float* fb = flow + (size_t)b * 2 * NPIX;
    float4 fx4 = *(const float4*)&fb[p];
    float4 fy4 = *(const float4*)&fb[p + NPIX];
    float fxs[4] = {fx4.x, fx4.y, fx4.z, fx4.w};
    float fys[4] = {fy4.x, fy4.y, fy4.z, fy4.w};
#pragma unroll
    for (int j = 0; j < 4; ++j) {
        float fx = fxs[j], fy = fys[j];
        if (fabsf(fx) < FMAX && fabsf(fy) < FMAX) continue;
        float x2 = (float)(x0 + j) + fx, y2 = (float)y + fy;
        if (!(x2 >= 0.f && y2 >= 0.f && x2 <= (float)(WW - 1) && y2 <= (float)(HH - 1)))
            continue;
        float d = depth[(size_t)b * NPIX + p + j];
        int pos = atomicAdd(&nOut[b], 1);
        if (pos < CAPB)
            lists[b * CAPB + pos] =
                make_int4(p + j, __float_as_int(fx), __float_as_int(fy), __float_as_int(d));
    }
}

// ---------------------------------------------------------------------------
// K2a: MIN pass (measured ~35us in R9). Unchanged.
// ---------------------------------------------------------------------------
__global__ void __launch_bounds__(TB, 4)
k2a_min(const float* __restrict__ flow, const float* __restrict__ depth,
        const int* __restrict__ nOut, const int4* __restrict__ lists,
        int* __restrict__ mindG) {
    __shared__ int mind_t[TPIX];

    int bid = blockIdx.x;
    { const int c = NT >> 3; bid = (bid & 7) * c + (bid >> 3); }
    const int b   = bid / TPB;
    const int tt  = bid - b * TPB;
    const int tty = tt / TILES_X;
    const int ty0 = tty * TH;
    const int tx0 = (tt - tty * TILES_X) * TW;
    const int tid = threadIdx.x;
    const float* flowb  = flow  + (size_t)b * 2 * NPIX;
    const float* depthb = depth + (size_t)b * NPIX;

    {
        const int IB = __float_as_int(1e30f);
        *(int4*)&mind_t[tid * 4] = make_int4(IB, IB, IB, IB);
    }
    __syncthreads();

    for (int s = tid; s < WPOS; s += TB) {
        int wy = s / WWIN;
        int wx = s - wy * WWIN;
        int gy = ty0 - RHALO + wy;
        int gx = tx0 - RHALO + wx;
        if ((unsigned)gy >= HH || (unsigned)gx >= WW) continue;
        int p = gy * WW + gx;
        float fx = flowb[p];
        float fy = flowb[p + NPIX];
        if (!(fabsf(fx) < FMAX && fabsf(fy) < FMAX)) continue;
        float x2 = (float)gx + fx, y2 = (float)gy + fy;
        if (!(x2 >= 0.f && y2 >= 0.f && x2 <= (float)(WW - 1) && y2 <= (float)(HH - 1)))
            continue;
        float d = depthb[p];
        int db = __float_as_int(d);
        int xL = (int)floorf(x2), yT = (int)floorf(y2);
        int xR = min(xL + 1, WW - 1), yB = min(yT + 1, HH - 1);
        int lxL = xL - tx0, lxR = xR - tx0, lyT = yT - ty0, lyB = yB - ty0;
        if ((unsigned)lyT < TH) {
            if ((unsigned)lxL < TW) atomicMin(&mind_t[lyT * TW + lxL], db);
            if ((unsigned)lxR < TW) atomicMin(&mind_t[lyT * TW + lxR], db);
        }
        if ((unsigned)lyB < TH) {
            if ((unsigned)lxL < TW) atomicMin(&mind_t[lyB * TW + lxL], db);
            if ((unsigned)lxR < TW) atomicMin(&mind_t[lyB * TW + lxR], db);
        }
    }
    const int nb = min(nOut[b], CAPB);
    for (int j = tid; j < nb; j += TB) {
        int4 e = lists[b * CAPB + j];
        float fx = __int_as_float(e.y), fy = __int_as_float(e.z);
        int y = e.x / WW, x = e.x - y * WW;
        float x2 = (float)x + fx, y2 = (float)y + fy;
        int xL = min(max((int)floorf(x2), 0), WW - 1);
        int yT = min(max((int)floorf(y2), 0), HH - 1);
        int xR = min(xL + 1, WW - 1), yB = min(yT + 1, HH - 1);
        int lxL = xL - tx0, lxR = xR - tx0, lyT = yT - ty0, lyB = yB - ty0;
        if ((unsigned)lyT < TH) {
            if ((unsigned)lxL < TW) atomicMin(&mind_t[lyT * TW + lxL], e.w);
            if ((unsigned)lxR < TW) atomicMin(&mind_t[lyT * TW + lxR], e.w);
        }
        if ((unsigned)lyB < TH) {
            if ((unsigned)lxL < TW) atomicMin(&mind_t[lyB * TW + lxL], e.w);
            if ((unsigned)lxR < TW) atomicMin(&mind_t[lyB * TW + lxR], e.w);
        }
    }
    __syncthreads();

    {
        int k4 = tid * 4;
        int ly = k4 >> 6;
        int lx = k4 & 63;
        int4 v = *(int4*)&mind_t[k4];
        *(int4*)&mindG[b * NPIX + (ty0 + ly) * WW + (tx0 + lx)] = v;
    }
}

// ---------------------------------------------------------------------------
// DIAGNOSTIC PROBES. Same tile mapping/LDS size/launch bounds as k2b.
// V0: streaming loads only.     V1: + decode.
// V2: + 4 scattered mindG gate reads.   V3: decode + ungated masked LDS adds.
// Results kept alive via asm volatile (no DCE). Write 1 float/block to sink.
// ---------------------------------------------------------------------------
template<int V>
__global__ void __launch_bounds__(TB, 4)
vd_probe(const float* __restrict__ flow, const float* __restrict__ depth,
         const int* __restrict__ mindG, float* __restrict__ sink) {
    __shared__ float sx_t[TPIX];
    __shared__ float sy_t[TPIX];
    __shared__ float cn_t[TPIX];

    int bid = blockIdx.x;
    { const int c = NT >> 3; bid = (bid & 7) * c + (bid >> 3); }
    const int b   = bid / TPB;
    const int tt  = bid - b * TPB;
    const int tty = tt / TILES_X;
    const int ty0 = tty * TH;
    const int tx0 = (tt - tty * TILES_X) * TW;
    const int tid = threadIdx.x;
    const float* flowb  = flow  + (size_t)b * 2 * NPIX;
    const float* depthb = depth + (size_t)b * NPIX;
    const int*   mindb  = mindG + b * NPIX;

    {
        int k4 = tid * 4;
        float4 z = make_float4(0.f, 0.f, 0.f, 0.f);
        *(float4*)&sx_t[k4] = z;
        *(float4*)&sy_t[k4] = z;
        *(float4*)&cn_t[k4] = z;
    }
    __syncthreads();

    float acc = 0.f;
    for (int s = tid; s < WPOS; s += TB) {
        int wy = s / WWIN;
        int wx = s - wy * WWIN;
        int gy = ty0 - RHALO + wy;
        int gx = tx0 - RHALO + wx;
        if ((unsigned)gy >= HH || (unsigned)gx >= WW) continue;
        int p = gy * WW + gx;
        float fx = flowb[p];
        float fy = flowb[p + NPIX];
        if (V == 0) { acc += fx + fy + depthb[p]; continue; }
        if (!(fabsf(fx) < FMAX && fabsf(fy) < FMAX)) continue;
        float x2 = (float)gx + fx, y2 = (float)gy + fy;
        if (!(x2 >= 0.f && y2 >= 0.f && x2 <= (float)(WW - 1) && y2 <= (float)(HH - 1)))
            continue;
        float d = depthb[p];
        int db = __float_as_int(d);
        int xL = (int)floorf(x2), yT = (int)floorf(y2);
        int xR = min(xL + 1, WW - 1), yB = min(yT + 1, HH - 1);
        if (V == 1) { acc += (float)(xL + yT + xR + yB) + d; continue; }
        if (V == 2) {
            int v0 = mindb[yT * WW + xL];
            int v1 = mindb[yT * WW + xR];
            int v2 = mindb[yB * WW + xL];
            int v3 = mindb[yB * WW + xR];
            acc += (float)(v0 ^ v1 ^ v2 ^ v3) + (float)(db & 7);
            continue;
        }
        // V == 3: ungated masked LDS adds (upper bound on add cost)
        int lxL = xL - tx0, lxR = xR - tx0, lyT = yT - ty0, lyB = yB - ty0;
        bool o0 = (unsigned)lyT < TH && (unsigned)lxL < TW;
        bool o1 = (unsigned)lyT < TH && (unsigned)lxR < TW;
        bool o2 = (unsigned)lyB < TH && (unsigned)lxL < TW;
        bool o3 = (unsigned)lyB < TH && (unsigned)lxR < TW;
        if (o0) { int l = lyT * TW + lxL;
            atomicAdd(&sx_t[l], -fx); atomicAdd(&sy_t[l], -fy); atomicAdd(&cn_t[l], 1.f); }
        if (o1) { int l = lyT * TW + lxR;
            atomicAdd(&sx_t[l], -fx); atomicAdd(&sy_t[l], -fy); atomicAdd(&cn_t[l], 1.f); }
        if (o2) { int l = lyB * TW + lxL;
            atomicAdd(&sx_t[l], -fx); atomicAdd(&sy_t[l], -fy); atomicAdd(&cn_t[l], 1.f); }
        if (o3) { int l = lyB * TW + lxR;
            atomicAdd(&sx_t[l], -fx); atomicAdd(&sy_t[l], -fy); atomicAdd(&cn_t[l], 1.f); }
        acc += d;
    }
    asm volatile("" :: "v"(acc));            // keep everything upstream live
    __syncthreads();
    if (tid == 0) sink[blockIdx.x] = acc + cn_t[0] + sx_t[1] + sy_t[2];
}

// ---------------------------------------------------------------------------
// K2b: ADD pass (measured 128us in R9). Unchanged — produces the real output.
// ---------------------------------------------------------------------------
__global__ void __launch_bounds__(TB, 4)
k2b_add(const float* __restrict__ flow, const float* __restrict__ depth,
        const int* __restrict__ nOut, const int4* __restrict__ lists,
        const int* __restrict__ mindG, float* __restrict__ out) {
    __shared__ float sx_t[TPIX];
    __shared__ float sy_t[TPIX];
    __shared__ float cn_t[TPIX];

    int bid = blockIdx.x;
    { const int c = NT >> 3; bid = (bid & 7) * c + (bid >> 3); }
    const int b   = bid / TPB;
    const int tt  = bid - b * TPB;
    const int tty = tt / TILES_X;
    const int ty0 = tty * TH;
    const int tx0 = (tt - tty * TILES_X) * TW;
    const int tid = threadIdx.x;
    const float* flowb  = flow  + (size_t)b * 2 * NPIX;
    const float* depthb = depth + (size_t)b * NPIX;
    const int*   mindb  = mindG + b * NPIX;

    {
        int k4 = tid * 4;
        float4 z = make_float4(0.f, 0.f, 0.f, 0.f);
        *(float4*)&sx_t[k4] = z;
        *(float4*)&sy_t[k4] = z;
        *(float4*)&cn_t[k4] = z;
    }
    __syncthreads();

    for (int s = tid; s < WPOS; s += TB) {
        int wy = s / WWIN;
        int wx = s - wy * WWIN;
        int gy = ty0 - RHALO + wy;
        int gx = tx0 - RHALO + wx;
        if ((unsigned)gy >= HH || (unsigned)gx >= WW) continue;
        int p = gy * WW + gx;
        float fx = flowb[p];
        float fy = flowb[p + NPIX];
        if (!(fabsf(fx) < FMAX && fabsf(fy) < FMAX)) continue;
        float x2 = (float)gx + fx, y2 = (float)gy + fy;
        if (!(x2 >= 0.f && y2 >= 0.f && x2 <= (float)(WW - 1) && y2 <= (float)(HH - 1)))
            continue;
        float d = depthb[p];
        int db = __float_as_int(d);
        int xL = (int)floorf(x2), yT = (int)floorf(y2);
        int xR = min(xL + 1, WW - 1), yB = min(yT + 1, HH - 1);
        int v0 = mindb[yT * WW + xL];
        int v1 = mindb[yT * WW + xR];
        int v2 = mindb[yB * WW + xL];
        int v3 = mindb[yB * WW + xR];
        int lxL = xL - tx0, lxR = xR - tx0, lyT = yT - ty0, lyB = yB - ty0;
        bool o0 = (unsigned)lyT < TH && (unsigned)lxL < TW && v0 == db;
        bool o1 = (unsigned)lyT < TH && (unsigned)lxR < TW && v1 == db;
        bool o2 = (unsigned)lyB < TH && (unsigned)lxL < TW && v2 == db;
        bool o3 = (unsigned)lyB < TH && (unsigned)lxR < TW && v3 == db;
        if (o0) { int l = lyT * TW + lxL;
            atomicAdd(&sx_t[l], -fx); atomicAdd(&sy_t[l], -fy); atomicAdd(&cn_t[l], 1.f); }
        if (o1) { int l = lyT * TW + lxR;
            atomicAdd(&sx_t[l], -fx); atomicAdd(&sy_t[l], -fy); atomicAdd(&cn_t[l], 1.f); }
        if (o2) { int l = lyB * TW + lxL;
            atomicAdd(&sx_t[l], -fx); atomicAdd(&sy_t[l], -fy); atomicAdd(&cn_t[l], 1.f); }
        if (o3) { int l = lyB * TW + lxR;
            atomicAdd(&sx_t[l], -fx); atomicAdd(&sy_t[l], -fy); atomicAdd(&cn_t[l], 1.f); }
    }
    const int nb = min(nOut[b], CAPB);
    for (int j = tid; j < nb; j += TB) {
        int4 e = lists[b * CAPB + j];
        float fx = __int_as_float(e.y), fy = __int_as_float(e.z);
        int y = e.x / WW, x = e.x - y * WW;
        float x2 = (float)x + fx, y2 = (float)y + fy;
        int xL = min(max((int)floorf(x2), 0), WW - 1);
        int yT = min(max((int)floorf(y2), 0), HH - 1);
        int xR = min(xL + 1, WW - 1), yB = min(yT + 1, HH - 1);
        int gs[4] = { yT * WW + xL, yT * WW + xR, yB * WW + xL, yB * WW + xR };
#pragma unroll
        for (int c = 0; c < 4; ++c) {
            int g = gs[c];
            int ly = g / WW - ty0, lx = g - (g / WW) * WW - tx0;
            if ((unsigned)ly < TH && (unsigned)lx < TW && mindb[g] == e.w) {
                int l = ly * TW + lx;
                atomicAdd(&sx_t[l], -fx);
                atomicAdd(&sy_t[l], -fy);
                atomicAdd(&cn_t[l], 1.0f);
            }
        }
    }
    __syncthreads();

    {
        int k4 = tid * 4;
        int ly = k4 >> 6;
        int lx = k4 & 63;
        float4 s4 = *(float4*)&sx_t[k4];
        float4 t4 = *(float4*)&sy_t[k4];
        float4 c4 = *(float4*)&cn_t[k4];
        float4 ox, oy;
        ox.x = (c4.x > 0.f) ? s4.x / c4.x : 0.f;  oy.x = (c4.x > 0.f) ? t4.x / c4.x : 0.f;
        ox.y = (c4.y > 0.f) ? s4.y / c4.y : 0.f;  oy.y = (c4.y > 0.f) ? t4.y / c4.y : 0.f;
        ox.z = (c4.z > 0.f) ? s4.z / c4.z : 0.f;  oy.z = (c4.z > 0.f) ? t4.z / c4.z : 0.f;
        ox.w = (c4.w > 0.f) ? s4.w / c4.w : 0.f;  oy.w = (c4.w > 0.f) ? t4.w / c4.w : 0.f;
        size_t o = (size_t)b * 2 * NPIX + (size_t)(ty0 + ly) * WW + (tx0 + lx);
        *(float4*)&out[o]        = ox;
        *(float4*)&out[o + NPIX] = oy;
    }
}

extern "C" void kernel_launch(void* const* d_in, const int* in_sizes, int n_in,
                              void* d_out, int out_size, void* d_ws, size_t ws_size,
                              hipStream_t stream) {
    const float* flow  = (const float*)d_in[0];
    const float* depth = (const float*)d_in[1];
    float* out = (float*)d_out;

    int*   nOut  = (int*)d_ws;                                        // 64 B
    int4*  lists = (int4*)((char*)d_ws + 64);                         // 512 KB
    int*   mindG = (int*)((char*)d_ws + 64 + (size_t)NB * CAPB * 16); // 29.5 MB
    float* sink  = (float*)(mindG + TOTAL);                           // NT floats

    hipMemsetAsync(nOut, 0, 64, stream);
    k1_outliers<<<TOTAL / 4 / 256, 256, 0, stream>>>(flow, depth, nOut, lists);
    k2a_min<<<NT, TB, 0, stream>>>(flow, depth, nOut, lists, mindG);
    // --- diagnostic probes (read-only wrt real pipeline; write to sink) ---
    vd_probe<0><<<NT, TB, 0, stream>>>(flow, depth, mindG, sink);
    vd_probe<1><<<NT, TB, 0, stream>>>(flow, depth, mindG, sink);
    vd_probe<2><<<NT, TB, 0, stream>>>(flow, depth, mindG, sink);
    vd_probe<3><<<NT, TB, 0, stream>>>(flow, depth, mindG, sink);
    // --- real output ---
    k2b_add<<<NT, TB, 0, stream>>>(flow, depth, nOut, lists, mindG, out);
}

// Round 12
// 80.150 us; speedup vs baseline: 9.0661x; 9.0661x over previous
//
#include <hip/hip_runtime.h>

#define WW 1280
#define HH 720
#define NB 8
#define NPIX (HH * WW)            // 921600
#define TOTAL (NB * NPIX)         // 7372800

#define FMAX 4.0f                 // |flow| < 4 -> inlier
#define RHALO 4
#define TH 16                     // 720 = 45*16
#define TW 64                     // 1280 = 20*64
#define TPIX (TH * TW)            // 1024
#define TILES_X (WW / TW)         // 20
#define TILES_Y (HH / TH)         // 45
#define TPB (TILES_X * TILES_Y)   // 900
#define NT (NB * TPB)             // 7200
#define WH (TH + 2 * RHALO)       // 24
#define WWIN (TW + 2 * RHALO)     // 72
#define WPOS (WH * WWIN)          // 1728
#define TB 256
#define NITER 7                   // ceil(WPOS/TB)
#define CAPB 4096

typedef unsigned long long u64;

// Packed accumulator: [sumx:28 bits | sumy:28 bits | cnt:8 bits], fixed-point
// q = round((t + 2048) * 256), t = -f. Capacity: <=162 writers/target max
// (adversarial), 162*2^20 < 2^28 per field, cnt<=162<256 -> no carries.
__device__ __forceinline__ u64 enc_add(float fx, float fy) {
    unsigned qx = (unsigned)__float2int_rn((2048.0f - fx) * 256.0f);
    unsigned qy = (unsigned)__float2int_rn((2048.0f - fy) * 256.0f);
    return ((u64)qx << 36) | ((u64)qy << 8) | 1ULL;
}

// ---------------------------------------------------------------------------
// K1: per-batch outlier lists (valid target but |fx|>=4 or |fy|>=4).
// ---------------------------------------------------------------------------
__global__ void k1_outliers(const float* __restrict__ flow,
                            const float* __restrict__ depth,
                            int* __restrict__ nOut, int4* __restrict__ lists) {
    int i = blockIdx.x * blockDim.x + threadIdx.x;
    int p4 = i * 4;
    int b = p4 / NPIX;
    int p = p4 - b * NPIX;
    int y = p / WW;
    int x0 = p - y * WW;
    const float* fb = flow + (size_t)b * 2 * NPIX;
    float4 fx4 = *(const float4*)&fb[p];
    float4 fy4 = *(const float4*)&fb[p + NPIX];
    float fxs[4] = {fx4.x, fx4.y, fx4.z, fx4.w};
    float fys[4] = {fy4.x, fy4.y, fy4.z, fy4.w};
#pragma unroll
    for (int j = 0; j < 4; ++j) {
        float fx = fxs[j], fy = fys[j];
        if (fabsf(fx) < FMAX && fabsf(fy) < FMAX) continue;
        float x2 = (float)(x0 + j) + fx, y2 = (float)y + fy;
        if (!(x2 >= 0.f && y2 >= 0.f && x2 <= (float)(WW - 1) && y2 <= (float)(HH - 1)))
            continue;
        float d = depth[(size_t)b * NPIX + p + j];
        int pos = atomicAdd(&nOut[b], 1);
        if (pos < CAPB)
            lists[b * CAPB + pos] =
                make_int4(p + j, __float_as_int(fx), __float_as_int(fy), __float_as_int(d));
    }
}

// ---------------------------------------------------------------------------
// K2: fused gather. Single window scan with register replay (R8 structure).
// Min phase: read-gated LDS atomicMin. Add phase: ONE packed u64 atomicAdd
// per selected corner (was 3 f32 atomics) -> 3x fewer LDS atomic instrs.
// ---------------------------------------------------------------------------
__global__ void __launch_bounds__(TB, 4)
k2_gather(const float* __restrict__ flow, const float* __restrict__ depth,
          const int* __restrict__ nOut, const int4* __restrict__ lists,
          float* __restrict__ out) {
    __shared__ int mind_t[TPIX];     // 4 KB
    __shared__ u64 acc_t[TPIX];      // 8 KB

    int bid = blockIdx.x;
    { const int c = NT >> 3; bid = (bid & 7) * c + (bid >> 3); }  // XCD swizzle
    const int b   = bid / TPB;
    const int tt  = bid - b * TPB;
    const int tty = tt / TILES_X;
    const int ty0 = tty * TH;
    const int tx0 = (tt - tty * TILES_X) * TW;
    const int tid = threadIdx.x;
    const float* flowb  = flow  + (size_t)b * 2 * NPIX;
    const float* depthb = depth + (size_t)b * NPIX;

    {   // init
        int k4 = tid * 4;
        const int IB = __float_as_int(1e30f);
        *(int4*)&mind_t[k4] = make_int4(IB, IB, IB, IB);
        acc_t[k4 + 0] = 0ULL; acc_t[k4 + 1] = 0ULL;
        acc_t[k4 + 2] = 0ULL; acc_t[k4 + 3] = 0ULL;
    }
    __syncthreads();

    // ---- phase A: scalar window scan, capture regs, read-gated LDS min ----
    float    fxA[NITER], fyA[NITER];
    int      dbA[NITER];
    unsigned pkA[NITER];
#pragma unroll
    for (int it = 0; it < NITER; ++it) {
        pkA[it] = 0u;
        int s  = tid + it * TB;
        int wy = s / WWIN;
        int wx = s - wy * WWIN;
        int gy = ty0 - RHALO + wy;
        int gx = tx0 - RHALO + wx;
        if (s >= WPOS || (unsigned)gy >= HH || (unsigned)gx >= WW) continue;
        int p = gy * WW + gx;
        float fx = flowb[p];
        float fy = flowb[p + NPIX];
        float d  = depthb[p];
        fxA[it] = fx; fyA[it] = fy;
        int db = __float_as_int(d);
        dbA[it] = db;
        if (!(fabsf(fx) < FMAX && fabsf(fy) < FMAX)) continue;
        float x2 = (float)gx + fx, y2 = (float)gy + fy;
        if (!(x2 >= 0.f && y2 >= 0.f && x2 <= (float)(WW - 1) && y2 <= (float)(HH - 1)))
            continue;
        int xL = (int)floorf(x2), yT = (int)floorf(y2);
        int xR = min(xL + 1, WW - 1), yB = min(yT + 1, HH - 1);
        int cR = (xR == xL), cB = (yB == yT);
        int lxL = xL - tx0, lyT = yT - ty0;
        int lxR = lxL + (cR ^ 1), lyB = lyT + (cB ^ 1);
        pkA[it] = 0x80000000u | (unsigned)((lyT + 8) << 9) |
                  (unsigned)((lxL + 8) << 2) | (unsigned)(cR << 1) | (unsigned)cB;
        if ((unsigned)lyT < TH) {
            if ((unsigned)lxL < TW) {
                int l = lyT * TW + lxL;
                if (db < mind_t[l]) atomicMin(&mind_t[l], db);
            }
            if ((unsigned)lxR < TW) {
                int l = lyT * TW + lxR;
                if (db < mind_t[l]) atomicMin(&mind_t[l], db);
            }
        }
        if ((unsigned)lyB < TH) {
            if ((unsigned)lxL < TW) {
                int l = lyB * TW + lxL;
                if (db < mind_t[l]) atomicMin(&mind_t[l], db);
            }
            if ((unsigned)lxR < TW) {
                int l = lyB * TW + lxR;
                if (db < mind_t[l]) atomicMin(&mind_t[l], db);
            }
        }
    }
    // ---- outlier mins ----
    const int nb = min(nOut[b], CAPB);
    for (int j = tid; j < nb; j += TB) {
        int4 e = lists[b * CAPB + j];
        float fx = __int_as_float(e.y), fy = __int_as_float(e.z);
        int y = e.x / WW, x = e.x - y * WW;
        float x2 = (float)x + fx, y2 = (float)y + fy;
        int xL = min(max((int)floorf(x2), 0), WW - 1);
        int yT = min(max((int)floorf(y2), 0), HH - 1);
        int xR = min(xL + 1, WW - 1), yB = min(yT + 1, HH - 1);
        int lxL = xL - tx0, lxR = xR - tx0, lyT = yT - ty0, lyB = yB - ty0;
        if ((unsigned)lyT < TH) {
            if ((unsigned)lxL < TW) atomicMin(&mind_t[lyT * TW + lxL], e.w);
            if ((unsigned)lxR < TW) atomicMin(&mind_t[lyT * TW + lxR], e.w);
        }
        if ((unsigned)lyB < TH) {
            if ((unsigned)lxL < TW) atomicMin(&mind_t[lyB * TW + lxL], e.w);
            if ((unsigned)lxR < TW) atomicMin(&mind_t[lyB * TW + lxR], e.w);
        }
    }
    __syncthreads();

    // ---- phase B: replay from regs; batched gate reads, ONE u64 add/corner --
#pragma unroll
    for (int it = 0; it < NITER; ++it) {
        unsigned pk = pkA[it];
        bool va = (pk >> 31) != 0u;
        int lxL = (int)((pk >> 2) & 0x7Fu) - 8;
        int lyT = (int)((pk >> 9) & 0x1Fu) - 8;
        int lxR = lxL + 1 - (int)((pk >> 1) & 1u);
        int lyB = lyT + 1 - (int)(pk & 1u);
        bool o0 = va && (unsigned)lyT < TH && (unsigned)lxL < TW;
        bool o1 = va && (unsigned)lyT < TH && (unsigned)lxR < TW;
        bool o2 = va && (unsigned)lyB < TH && (unsigned)lxL < TW;
        bool o3 = va && (unsigned)lyB < TH && (unsigned)lxR < TW;
        int i0 = o0 ? lyT * TW + lxL : 0;
        int i1 = o1 ? lyT * TW + lxR : 0;
        int i2 = o2 ? lyB * TW + lxL : 0;
        int i3 = o3 ? lyB * TW + lxR : 0;
        int v0 = mind_t[i0];          // 4 independent reads -> one wait
        int v1 = mind_t[i1];
        int v2 = mind_t[i2];
        int v3 = mind_t[i3];
        float fx = fxA[it], fy = fyA[it];
        int db = dbA[it];
        u64 enc = enc_add(fx, fy);    // same payload for all 4 corners
        if (o0 && v0 == db) atomicAdd(&acc_t[i0], enc);
        if (o1 && v1 == db) atomicAdd(&acc_t[i1], enc);
        if (o2 && v2 == db) atomicAdd(&acc_t[i2], enc);
        if (o3 && v3 == db) atomicAdd(&acc_t[i3], enc);
    }
    // ---- outlier adds (packed, same encoding; bias 2048 covers |f|<1280) ----
    for (int j = tid; j < nb; j += TB) {
        int4 e = lists[b * CAPB + j];
        float fx = __int_as_float(e.y), fy = __int_as_float(e.z);
        int y = e.x / WW, x = e.x - y * WW;
        float x2 = (float)x + fx, y2 = (float)y + fy;
        int xL = min(max((int)floorf(x2), 0), WW - 1);
        int yT = min(max((int)floorf(y2), 0), HH - 1);
        int xR = min(xL + 1, WW - 1), yB = min(yT + 1, HH - 1);
        int lxL = xL - tx0, lxR = xR - tx0, lyT = yT - ty0, lyB = yB - ty0;
        u64 enc = enc_add(fx, fy);
        int ls[4] = {
            ((unsigned)lyT < TH && (unsigned)lxL < TW) ? lyT * TW + lxL : -1,
            ((unsigned)lyT < TH && (unsigned)lxR < TW) ? lyT * TW + lxR : -1,
            ((unsigned)lyB < TH && (unsigned)lxL < TW) ? lyB * TW + lxL : -1,
            ((unsigned)lyB < TH && (unsigned)lxR < TW) ? lyB * TW + lxR : -1 };
#pragma unroll
        for (int c = 0; c < 4; ++c) {
            int l = ls[c];
            if (l >= 0 && mind_t[l] == e.w) atomicAdd(&acc_t[l], enc);
        }
    }
    __syncthreads();

    // ---- epilogue: unpack (double for exactness), divide, float4 store ----
    {
        int k4 = tid * 4;
        int ly = k4 >> 6;
        int lx = k4 & 63;
        float ox[4], oy[4];
#pragma unroll
        for (int j = 0; j < 4; ++j) {
            u64 v = acc_t[k4 + j];
            unsigned cnt  = (unsigned)(v & 0xFFULL);
            unsigned ysum = (unsigned)((v >> 8) & 0xFFFFFFFULL);
            unsigned xsum = (unsigned)(v >> 36);
            if (cnt) {
                double c = (double)cnt;
                double sx = (double)xsum * (1.0 / 256.0) - 2048.0 * c;
                double sy = (double)ysum * (1.0 / 256.0) - 2048.0 * c;
                ox[j] = (float)(sx / c);
                oy[j] = (float)(sy / c);
            } else {
                ox[j] = 0.f; oy[j] = 0.f;
            }
        }
        size_t o = (size_t)b * 2 * NPIX + (size_t)(ty0 + ly) * WW + (tx0 + lx);
        *(float4*)&out[o]        = make_float4(ox[0], ox[1], ox[2], ox[3]);
        *(float4*)&out[o + NPIX] = make_float4(oy[0], oy[1], oy[2], oy[3]);
    }
}

extern "C" void kernel_launch(void* const* d_in, const int* in_sizes, int n_in,
                              void* d_out, int out_size, void* d_ws, size_t ws_size,
                              hipStream_t stream) {
    const float* flow  = (const float*)d_in[0];
    const float* depth = (const float*)d_in[1];
    float* out = (float*)d_out;

    int*  nOut  = (int*)d_ws;                 // 16 ints (first NB used)
    int4* lists = (int4*)((char*)d_ws + 64);  // NB * CAPB entries

    hipMemsetAsync(nOut, 0, 64, stream);
    k1_outliers<<<TOTAL / 4 / 256, 256, 0, stream>>>(flow, depth, nOut, lists);
    k2_gather  <<<NT, TB, 0, stream>>>(flow, depth, nOut, lists, out);
}